// Round 4
// baseline (824.889 us; speedup 1.0000x reference)
//
#include <hip/hip_runtime.h>

#define F 128
#define SCANB 1024
#define MAXB 1024   // max buckets

typedef __attribute__((ext_vector_type(8))) short short8;
typedef __attribute__((ext_vector_type(4))) float f32x4;

static __device__ __forceinline__ short f2bf(float f) {
    union { float f; unsigned u; } v; v.f = f;
    unsigned r = v.u + 0x7FFF + ((v.u >> 16) & 1);   // round-to-nearest-even
    return (short)(r >> 16);
}
static __device__ __forceinline__ float bf_lo(unsigned u) {
    return __builtin_bit_cast(float, u << 16);
}
static __device__ __forceinline__ float bf_hi(unsigned u) {
    return __builtin_bit_cast(float, u & 0xFFFF0000u);
}

// ---------- pass A1: per-node deg histogram + per-bucket edge counts ----------
__global__ __launch_bounds__(256) void k_bin_count(
    const int* __restrict__ dst, int* __restrict__ deg,
    int* __restrict__ bcnt, int n_edges, int nb, int bshift) {
    __shared__ int lh[MAXB];
    for (int i = threadIdx.x; i < nb; i += 256) lh[i] = 0;
    __syncthreads();
    for (int e = blockIdx.x * 256 + threadIdx.x; e < n_edges; e += gridDim.x * 256) {
        int d = dst[e];
        atomicAdd(&deg[d], 1);
        atomicAdd(&lh[d >> bshift], 1);
    }
    __syncthreads();
    for (int i = threadIdx.x; i < nb; i += 256) {
        int v = lh[i];
        if (v) atomicAdd(&bcnt[i], v);
    }
}

// ---------- bucket scan: exclusive scan of bcnt -> boff, zero bcur ----------
__global__ __launch_bounds__(MAXB) void k_bin_scan(
    const int* __restrict__ bcnt, int* __restrict__ boff,
    int* __restrict__ bcur, int nb) {
    __shared__ int tmp[MAXB];
    int i = threadIdx.x;
    int v = (i < nb) ? bcnt[i] : 0;
    tmp[i] = v;
    __syncthreads();
    for (int off = 1; off < MAXB; off <<= 1) {
        int t = (i >= off) ? tmp[i - off] : 0;
        __syncthreads();
        tmp[i] += t;
        __syncthreads();
    }
    if (i < nb) { boff[i] = tmp[i] - v; bcur[i] = 0; }
}

// ---------- pass A2: scatter (src,dst) pairs into bucket-major order ----------
__global__ __launch_bounds__(256) void k_bin_scatter(
    const int* __restrict__ src, const int* __restrict__ dst,
    const int* __restrict__ boff, int* __restrict__ bcur,
    int2* __restrict__ binned, int n_edges, int bshift) {
    int e = blockIdx.x * 256 + threadIdx.x;
    if (e >= n_edges) return;
    int d = dst[e];
    int b = d >> bshift;
    int pos = boff[b] + atomicAdd(&bcur[b], 1);
    binned[pos] = make_int2(src[e], d);
}

// ---------- pass B: per-bucket CSR finalize (localized esrc writes) ----------
__global__ __launch_bounds__(256) void k_bin_to_csr(
    const int2* __restrict__ binned, const int* __restrict__ boff,
    const int* __restrict__ bcnt, const int* __restrict__ offs,
    int* __restrict__ cursor, int* __restrict__ esrc) {
    int b = blockIdx.x;
    int start = boff[b], cnt = bcnt[b];
    for (int i = threadIdx.x; i < cnt; i += 256) {
        int2 p = binned[start + i];
        int pos = offs[p.y] + atomicAdd(&cursor[p.y], 1);
        esrc[pos] = p.x;
    }
}

// ---------- node-level exclusive scan over deg ----------
__global__ __launch_bounds__(SCANB) void k_scan_a(const int* __restrict__ deg,
                                                  int* __restrict__ offs,
                                                  int* __restrict__ bsum, int n) {
    __shared__ int tmp[SCANB];
    int i = blockIdx.x * SCANB + threadIdx.x;
    int v = (i < n) ? deg[i] : 0;
    tmp[threadIdx.x] = v;
    __syncthreads();
    for (int off = 1; off < SCANB; off <<= 1) {
        int t = (threadIdx.x >= off) ? tmp[threadIdx.x - off] : 0;
        __syncthreads();
        tmp[threadIdx.x] += t;
        __syncthreads();
    }
    if (i < n) offs[i] = tmp[threadIdx.x] - v;
    if (threadIdx.x == SCANB - 1) bsum[blockIdx.x] = tmp[SCANB - 1];
}

__global__ void k_scan_b(int* bsum, int nb) {
    if (threadIdx.x == 0 && blockIdx.x == 0) {
        int run = 0;
        for (int b = 0; b < nb; ++b) { int t = bsum[b]; bsum[b] = run; run += t; }
    }
}

__global__ __launch_bounds__(SCANB) void k_scan_c(int* __restrict__ offs,
                                                  const int* __restrict__ bsum, int n) {
    int i = blockIdx.x * SCANB + threadIdx.x;
    if (i < n) offs[i] += bsum[blockIdx.x];
}

// ---------- fallback: direct CSR scatter (round-2 path) ----------
__global__ __launch_bounds__(256) void k_hist(const int* __restrict__ dst,
                                              int* __restrict__ deg, int n_edges) {
    int e = blockIdx.x * 256 + threadIdx.x;
    if (e < n_edges) atomicAdd(&deg[dst[e]], 1);
}

__global__ __launch_bounds__(256) void k_scatter_idx(
    const int* __restrict__ src, const int* __restrict__ dst,
    const int* __restrict__ offs, int* __restrict__ cursor,
    int* __restrict__ esrc, int n_edges) {
    int e = blockIdx.x * 256 + threadIdx.x;
    if (e >= n_edges) return;
    int d = dst[e];
    int pos = offs[d] + atomicAdd(&cursor[d], 1);
    esrc[pos] = src[e];
}

// ---------- h (f32) -> hb (bf16 packed pairs) ----------
__global__ __launch_bounds__(256) void k_h2b(const float* __restrict__ h,
                                             unsigned* __restrict__ hb, int total8) {
    int t = blockIdx.x * 256 + threadIdx.x;
    if (t >= total8) return;
    const float4* hp = (const float4*)h;
    float4 a = hp[t * 2], b = hp[t * 2 + 1];
    uint4 o;
    o.x = ((unsigned)(unsigned short)f2bf(a.y) << 16) | (unsigned short)f2bf(a.x);
    o.y = ((unsigned)(unsigned short)f2bf(a.w) << 16) | (unsigned short)f2bf(a.z);
    o.z = ((unsigned)(unsigned short)f2bf(b.y) << 16) | (unsigned short)f2bf(b.x);
    o.w = ((unsigned)(unsigned short)f2bf(b.w) << 16) | (unsigned short)f2bf(b.z);
    ((uint4*)hb)[t] = o;
}

// ---------- gather-sum from bf16 h: one wave per node ----------
__global__ __launch_bounds__(256) void k_gather_bf16(
    const unsigned* __restrict__ hb, const int* __restrict__ esrc,
    const int* __restrict__ offs, const int* __restrict__ deg,
    float* __restrict__ x, int n_nodes) {
    int t = blockIdx.x * 256 + threadIdx.x;
    int node = t >> 6;
    int lane = t & 63;
    if (node >= n_nodes) return;
    int start = offs[node];
    int dn = deg[node];
    float ax = 0.0f, ay = 0.0f;
    int i = 0;
    for (; i + 4 <= dn; i += 4) {
        int s0 = esrc[start + i + 0], s1 = esrc[start + i + 1];
        int s2 = esrc[start + i + 2], s3 = esrc[start + i + 3];
        unsigned u0 = hb[(size_t)s0 * 64 + lane];
        unsigned u1 = hb[(size_t)s1 * 64 + lane];
        unsigned u2 = hb[(size_t)s2 * 64 + lane];
        unsigned u3 = hb[(size_t)s3 * 64 + lane];
        ax += (bf_lo(u0) + bf_lo(u1)) + (bf_lo(u2) + bf_lo(u3));
        ay += (bf_hi(u0) + bf_hi(u1)) + (bf_hi(u2) + bf_hi(u3));
    }
    for (; i < dn; ++i) {
        int s = esrc[start + i];
        unsigned u = hb[(size_t)s * 64 + lane];
        ax += bf_lo(u); ay += bf_hi(u);
    }
    float nv = dn > 0 ? 1.0f / (float)dn : 0.0f;
    ((float2*)x)[(size_t)node * 64 + lane] = make_float2(ax * nv, ay * nv);
}

// ---------- gather-sum from f32 h (fallback) ----------
__global__ __launch_bounds__(256) void k_gather_f32(
    const float* __restrict__ h, const int* __restrict__ esrc,
    const int* __restrict__ offs, const int* __restrict__ deg,
    float* __restrict__ x, int n_nodes) {
    int t = blockIdx.x * 256 + threadIdx.x;
    int node = t >> 6;
    int lane = t & 63;
    if (node >= n_nodes) return;
    int start = offs[node];
    int dn = deg[node];
    const float2* hp = (const float2*)h;
    float ax = 0.0f, ay = 0.0f;
    int i = 0;
    for (; i + 4 <= dn; i += 4) {
        int s0 = esrc[start + i + 0], s1 = esrc[start + i + 1];
        int s2 = esrc[start + i + 2], s3 = esrc[start + i + 3];
        float2 v0 = hp[(size_t)s0 * 64 + lane];
        float2 v1 = hp[(size_t)s1 * 64 + lane];
        float2 v2 = hp[(size_t)s2 * 64 + lane];
        float2 v3 = hp[(size_t)s3 * 64 + lane];
        ax += (v0.x + v1.x) + (v2.x + v3.x);
        ay += (v0.y + v1.y) + (v2.y + v3.y);
    }
    for (; i < dn; ++i) {
        int s = esrc[start + i];
        float2 v = hp[(size_t)s * 64 + lane];
        ax += v.x; ay += v.y;
    }
    float nv = dn > 0 ? 1.0f / (float)dn : 0.0f;
    ((float2*)x)[(size_t)node * 64 + lane] = make_float2(ax * nv, ay * nv);
}

// ---------- MFMA transform: x_norm @ W + bias -> LayerNorm -> ReLU ----------
__global__ __launch_bounds__(256) void k_transform_mfma(
    const float* __restrict__ w, const float* __restrict__ bias,
    const float* __restrict__ gamma, const float* __restrict__ beta,
    float* __restrict__ x, int n_nodes) {
    __shared__ short wt[128 * 136];   // wt[col][k], padded stride

    const int tid = threadIdx.x;
    {
        int n = tid & 127;
        for (int k = tid >> 7; k < 128; k += 2)
            wt[n * 136 + k] = f2bf(w[(size_t)k * 128 + n]);
    }
    __syncthreads();

    const int wid = tid >> 6;
    const int l   = tid & 63;
    const int lr  = l & 15;
    const int lk  = l >> 4;

    float bs[8], gm[8], bt[8];
    #pragma unroll
    for (int n = 0; n < 8; ++n) {
        int c = n * 16 + lr;
        bs[n] = bias[c]; gm[n] = gamma[c]; bt[n] = beta[c];
    }

    for (int base = blockIdx.x * 64; base < n_nodes; base += gridDim.x * 64) {
        const int row = base + wid * 16 + lr;
        const bool valid = row < n_nodes;

        short8 af[4];
        #pragma unroll
        for (int kk = 0; kk < 4; ++kk) {
            int k0 = kk * 32 + lk * 8;
            float4 a0{0,0,0,0}, a1{0,0,0,0};
            if (valid) {
                a0 = *(const float4*)(x + (size_t)row * F + k0);
                a1 = *(const float4*)(x + (size_t)row * F + k0 + 4);
            }
            af[kk] = short8{ f2bf(a0.x), f2bf(a0.y), f2bf(a0.z), f2bf(a0.w),
                             f2bf(a1.x), f2bf(a1.y), f2bf(a1.z), f2bf(a1.w) };
        }

        f32x4 acc[8];
        #pragma unroll
        for (int n = 0; n < 8; ++n) acc[n] = f32x4{0, 0, 0, 0};

        #pragma unroll
        for (int kk = 0; kk < 4; ++kk) {
            const int kb = kk * 32 + lk * 8;
            #pragma unroll
            for (int n = 0; n < 8; ++n) {
                short8 bfr = *(const short8*)(&wt[(n * 16 + lr) * 136 + kb]);
                acc[n] = __builtin_amdgcn_mfma_f32_16x16x32_bf16(af[kk], bfr, acc[n], 0, 0, 0);
            }
        }

        float s4[4] = {0,0,0,0}, q4[4] = {0,0,0,0};
        #pragma unroll
        for (int n = 0; n < 8; ++n)
            #pragma unroll
            for (int r = 0; r < 4; ++r) {
                float v = acc[n][r] + bs[n];
                acc[n][r] = v;
                s4[r] += v; q4[r] += v * v;
            }
        #pragma unroll
        for (int m = 1; m < 16; m <<= 1)
            #pragma unroll
            for (int r = 0; r < 4; ++r) {
                s4[r] += __shfl_xor(s4[r], m);
                q4[r] += __shfl_xor(q4[r], m);
            }

        #pragma unroll
        for (int r = 0; r < 4; ++r) {
            float mu   = s4[r] * (1.0f / F);
            float var  = q4[r] * (1.0f / F) - mu * mu;
            float rstd = rsqrtf(var + 1e-5f);
            int rw = base + wid * 16 + lk * 4 + r;
            if (rw < n_nodes) {
                #pragma unroll
                for (int n = 0; n < 8; ++n) {
                    float y = (acc[n][r] - mu) * rstd * gm[n] + bt[n];
                    x[(size_t)rw * F + n * 16 + lr] = fmaxf(y, 0.0f);
                }
            }
        }
    }
}

extern "C" void kernel_launch(void* const* d_in, const int* in_sizes, int n_in,
                              void* d_out, int out_size, void* d_ws, size_t ws_size,
                              hipStream_t stream) {
    const float* h      = (const float*)d_in[0];
    const float* weight = (const float*)d_in[1];
    const float* bias   = (const float*)d_in[2];
    const float* gamma  = (const float*)d_in[3];
    const float* beta   = (const float*)d_in[4];
    const int*   src    = (const int*)d_in[5];
    const int*   dst    = (const int*)d_in[6];

    const int n_nodes = in_sizes[0] / F;
    const int n_edges = in_sizes[5];

    float* x = (float*)d_out;   // N x 128: x_norm after gather, output after transform

    // choose bucket shift so NB <= MAXB
    int bshift = 8;
    while (((n_nodes + (1 << bshift) - 1) >> bshift) > MAXB) ++bshift;
    const int nb = (n_nodes + (1 << bshift) - 1) >> bshift;

    // ws ints: deg[N] | cursor[N] | offs[N] | bsum[256] | bcnt[1024] | boff[1024]
    //          | bcur[1024] | esrc[E] | hb[N*64 u32] | binned[E int2]
    const int nscan = (n_nodes + SCANB - 1) / SCANB;
    int* deg    = (int*)d_ws;
    int* cursor = deg + n_nodes;
    int* offs   = cursor + n_nodes;
    int* bsum   = offs + n_nodes;
    int* bcnt   = bsum + 256;
    int* boff   = bcnt + MAXB;
    int* bcur   = boff + MAXB;
    int* esrc   = bcur + MAXB;
    unsigned* hb = (unsigned*)(esrc + n_edges);
    int2* binned = (int2*)(hb + (size_t)n_nodes * 64);

    size_t need_base = ((size_t)3 * n_nodes + 256 + 3 * MAXB + (size_t)n_edges) * sizeof(int);
    size_t need_bf16 = need_base + (size_t)n_nodes * 64 * sizeof(unsigned);
    size_t need_bin  = need_bf16 + (size_t)n_edges * sizeof(int2);
    bool use_bf16 = ws_size >= need_bf16;
    bool use_bin  = ws_size >= need_bin;

    hipMemsetAsync(deg, 0, (size_t)2 * n_nodes * sizeof(int), stream);
    hipMemsetAsync(bcnt, 0, MAXB * sizeof(int), stream);

    if (use_bf16) {
        int total8 = n_nodes * F / 8;
        k_h2b<<<(total8 + 255) / 256, 256, 0, stream>>>(h, hb, total8);
    }

    if (use_bin) {
        k_bin_count<<<1024, 256, 0, stream>>>(dst, deg, bcnt, n_edges, nb, bshift);
        k_scan_a<<<nscan, SCANB, 0, stream>>>(deg, offs, bsum, n_nodes);
        k_scan_b<<<1, 64, 0, stream>>>(bsum, nscan);
        k_scan_c<<<nscan, SCANB, 0, stream>>>(offs, bsum, n_nodes);
        k_bin_scan<<<1, MAXB, 0, stream>>>(bcnt, boff, bcur, nb);
        k_bin_scatter<<<(n_edges + 255) / 256, 256, 0, stream>>>(
            src, dst, boff, bcur, binned, n_edges, bshift);
        k_bin_to_csr<<<nb, 256, 0, stream>>>(binned, boff, bcnt, offs, cursor, esrc);
    } else {
        k_hist<<<(n_edges + 255) / 256, 256, 0, stream>>>(dst, deg, n_edges);
        k_scan_a<<<nscan, SCANB, 0, stream>>>(deg, offs, bsum, n_nodes);
        k_scan_b<<<1, 64, 0, stream>>>(bsum, nscan);
        k_scan_c<<<nscan, SCANB, 0, stream>>>(offs, bsum, n_nodes);
        k_scatter_idx<<<(n_edges + 255) / 256, 256, 0, stream>>>(
            src, dst, offs, cursor, esrc, n_edges);
    }

    int gblocks = (int)(((size_t)n_nodes * 64 + 255) / 256);
    if (use_bf16)
        k_gather_bf16<<<gblocks, 256, 0, stream>>>(hb, esrc, offs, deg, x, n_nodes);
    else
        k_gather_f32<<<gblocks, 256, 0, stream>>>(h, esrc, offs, deg, x, n_nodes);

    int tblocks = (n_nodes + 63) / 64;
    k_transform_mfma<<<tblocks, 256, 0, stream>>>(weight, bias, gamma, beta, x, n_nodes);
}

// Round 5
// 201.177 us; speedup vs baseline: 4.1003x; 4.1003x over previous
//
#include <hip/hip_runtime.h>

#define F 128
#define SCANB 1024
#define NBLK 128      // partition blocks
#define MAXNB 4096    // max buckets
#define MAXBS 64      // max nodes per bucket (bshift <= 6)

typedef __attribute__((ext_vector_type(8))) short short8;
typedef __attribute__((ext_vector_type(4))) float f32x4;

static __device__ __forceinline__ short f2bf(float f) {
    union { float f; unsigned u; } v; v.f = f;
    unsigned r = v.u + 0x7FFF + ((v.u >> 16) & 1);   // round-to-nearest-even
    return (short)(r >> 16);
}
static __device__ __forceinline__ float bf_lo(unsigned u) {
    return __builtin_bit_cast(float, u << 16);
}
static __device__ __forceinline__ float bf_hi(unsigned u) {
    return __builtin_bit_cast(float, u & 0xFFFF0000u);
}

// ========== atomic-free partition: pass 1 — per-(bucket,block) counts ======
__global__ __launch_bounds__(256) void k_part_hist(
    const int* __restrict__ dst, int* __restrict__ mat,
    int n_edges, int nb, int bshift, int epb) {
    __shared__ int lh[MAXNB];
    for (int i = threadIdx.x; i < nb; i += 256) lh[i] = 0;
    __syncthreads();
    int e0 = blockIdx.x * epb;
    int e1 = min(e0 + epb, n_edges);
    for (int e = e0 + threadIdx.x; e < e1; e += 256)
        atomicAdd(&lh[dst[e] >> bshift], 1);
    __syncthreads();
    for (int i = threadIdx.x; i < nb; i += 256)
        mat[(size_t)i * NBLK + blockIdx.x] = lh[i];
}

// ========== exclusive scan (generic, also used in-place on mat) ============
__global__ __launch_bounds__(SCANB) void k_scan_a(const int* in, int* out,
                                                  int* bsum, int n) {
    __shared__ int tmp[SCANB];
    int i = blockIdx.x * SCANB + threadIdx.x;
    int v = (i < n) ? in[i] : 0;
    tmp[threadIdx.x] = v;
    __syncthreads();
    for (int off = 1; off < SCANB; off <<= 1) {
        int t = (threadIdx.x >= off) ? tmp[threadIdx.x - off] : 0;
        __syncthreads();
        tmp[threadIdx.x] += t;
        __syncthreads();
    }
    if (i < n) out[i] = tmp[threadIdx.x] - v;
    if (threadIdx.x == SCANB - 1) bsum[blockIdx.x] = tmp[SCANB - 1];
}

__global__ __launch_bounds__(512) void k_scan_b(int* bsum, int nb) {
    __shared__ int tmp[512];
    int i = threadIdx.x;
    int v = (i < nb) ? bsum[i] : 0;
    tmp[i] = v;
    __syncthreads();
    for (int off = 1; off < 512; off <<= 1) {
        int t = (i >= off) ? tmp[i - off] : 0;
        __syncthreads();
        tmp[i] += t;
        __syncthreads();
    }
    if (i < nb) bsum[i] = tmp[i] - v;
}

__global__ __launch_bounds__(SCANB) void k_scan_c(int* out, const int* bsum, int n) {
    int i = blockIdx.x * SCANB + threadIdx.x;
    if (i < n) out[i] += bsum[blockIdx.x];
}

// ========== pass 2 — scatter packed edges, zero global atomics =============
__global__ __launch_bounds__(256) void k_part_scatter(
    const int* __restrict__ src, const int* __restrict__ dst,
    const int* __restrict__ mat, unsigned* __restrict__ binned,
    int n_edges, int nb, int bshift, int epb) {
    __shared__ int lbase[MAXNB];
    int e0 = blockIdx.x * epb;
    int e1 = min(e0 + epb, n_edges);
    for (int i = threadIdx.x; i < nb; i += 256)
        lbase[i] = mat[(size_t)i * NBLK + blockIdx.x];
    __syncthreads();
    for (int e = e0 + threadIdx.x; e < e1; e += 256) {
        int d = dst[e];
        int b = d >> bshift;
        int pos = atomicAdd(&lbase[b], 1);   // LDS atomic only
        binned[pos] = ((unsigned)(d & ((1 << bshift) - 1)) << 26) | (unsigned)src[e];
    }
}

// ========== pass 3 — per-bucket CSR finalize (deg/offs/esrc, all local) ====
__global__ __launch_bounds__(256) void k_bin_to_csr(
    const unsigned* __restrict__ binned, const int* __restrict__ mat,
    int* __restrict__ deg, int* __restrict__ offs, int* __restrict__ esrc,
    int n_edges, int n_nodes, int nb, int bshift) {
    __shared__ int ldeg[MAXBS], loffs[MAXBS], lcur[MAXBS];
    int b = blockIdx.x;
    int start = mat[(size_t)b * NBLK];
    int end   = (b + 1 < nb) ? mat[(size_t)(b + 1) * NBLK] : n_edges;
    int cnt = end - start;
    int base_node = b << bshift;
    int nn = min(1 << bshift, n_nodes - base_node);
    for (int i = threadIdx.x; i < nn; i += 256) { ldeg[i] = 0; lcur[i] = 0; }
    __syncthreads();
    for (int i = threadIdx.x; i < cnt; i += 256)
        atomicAdd(&ldeg[binned[start + i] >> 26], 1);
    __syncthreads();
    if (threadIdx.x == 0) {
        int run = 0;
        for (int i = 0; i < nn; ++i) { loffs[i] = run; run += ldeg[i]; }
    }
    __syncthreads();
    for (int i = threadIdx.x; i < nn; i += 256) {
        deg[base_node + i]  = ldeg[i];
        offs[base_node + i] = start + loffs[i];
    }
    for (int i = threadIdx.x; i < cnt; i += 256) {
        unsigned p = binned[start + i];
        int ln = p >> 26;
        int pos = start + loffs[ln] + atomicAdd(&lcur[ln], 1);  // LDS atomic
        esrc[pos] = (int)(p & ((1u << 26) - 1));
    }
}

// ========== fallback CSR build (round-3 direct path) =======================
__global__ __launch_bounds__(256) void k_hist(const int* __restrict__ dst,
                                              int* __restrict__ deg, int n_edges) {
    int e = blockIdx.x * 256 + threadIdx.x;
    if (e < n_edges) atomicAdd(&deg[dst[e]], 1);
}

__global__ __launch_bounds__(256) void k_scatter_idx(
    const int* __restrict__ src, const int* __restrict__ dst,
    const int* __restrict__ offs, int* __restrict__ cursor,
    int* __restrict__ esrc, int n_edges) {
    int e = blockIdx.x * 256 + threadIdx.x;
    if (e >= n_edges) return;
    int d = dst[e];
    int pos = offs[d] + atomicAdd(&cursor[d], 1);
    esrc[pos] = src[e];
}

// ========== h (f32) -> hb (bf16 packed pairs) ==============================
__global__ __launch_bounds__(256) void k_h2b(const float* __restrict__ h,
                                             unsigned* __restrict__ hb, int total8) {
    int t = blockIdx.x * 256 + threadIdx.x;
    if (t >= total8) return;
    const float4* hp = (const float4*)h;
    float4 a = hp[t * 2], b = hp[t * 2 + 1];
    uint4 o;
    o.x = ((unsigned)(unsigned short)f2bf(a.y) << 16) | (unsigned short)f2bf(a.x);
    o.y = ((unsigned)(unsigned short)f2bf(a.w) << 16) | (unsigned short)f2bf(a.z);
    o.z = ((unsigned)(unsigned short)f2bf(b.y) << 16) | (unsigned short)f2bf(b.x);
    o.w = ((unsigned)(unsigned short)f2bf(b.w) << 16) | (unsigned short)f2bf(b.z);
    ((uint4*)hb)[t] = o;
}

// ========== gather-sum from bf16 h: one wave per node ======================
__global__ __launch_bounds__(256) void k_gather_bf16(
    const unsigned* __restrict__ hb, const int* __restrict__ esrc,
    const int* __restrict__ offs, const int* __restrict__ deg,
    float* __restrict__ x, int n_nodes) {
    int t = blockIdx.x * 256 + threadIdx.x;
    int node = t >> 6;
    int lane = t & 63;
    if (node >= n_nodes) return;
    int start = offs[node];
    int dn = deg[node];
    float ax = 0.0f, ay = 0.0f;
    int i = 0;
    for (; i + 4 <= dn; i += 4) {
        int s0 = esrc[start + i + 0], s1 = esrc[start + i + 1];
        int s2 = esrc[start + i + 2], s3 = esrc[start + i + 3];
        unsigned u0 = hb[(size_t)s0 * 64 + lane];
        unsigned u1 = hb[(size_t)s1 * 64 + lane];
        unsigned u2 = hb[(size_t)s2 * 64 + lane];
        unsigned u3 = hb[(size_t)s3 * 64 + lane];
        ax += (bf_lo(u0) + bf_lo(u1)) + (bf_lo(u2) + bf_lo(u3));
        ay += (bf_hi(u0) + bf_hi(u1)) + (bf_hi(u2) + bf_hi(u3));
    }
    for (; i < dn; ++i) {
        int s = esrc[start + i];
        unsigned u = hb[(size_t)s * 64 + lane];
        ax += bf_lo(u); ay += bf_hi(u);
    }
    float nv = dn > 0 ? 1.0f / (float)dn : 0.0f;
    ((float2*)x)[(size_t)node * 64 + lane] = make_float2(ax * nv, ay * nv);
}

// ========== gather-sum from f32 h (fallback) ===============================
__global__ __launch_bounds__(256) void k_gather_f32(
    const float* __restrict__ h, const int* __restrict__ esrc,
    const int* __restrict__ offs, const int* __restrict__ deg,
    float* __restrict__ x, int n_nodes) {
    int t = blockIdx.x * 256 + threadIdx.x;
    int node = t >> 6;
    int lane = t & 63;
    if (node >= n_nodes) return;
    int start = offs[node];
    int dn = deg[node];
    const float2* hp = (const float2*)h;
    float ax = 0.0f, ay = 0.0f;
    for (int i = 0; i < dn; ++i) {
        int s = esrc[start + i];
        float2 v = hp[(size_t)s * 64 + lane];
        ax += v.x; ay += v.y;
    }
    float nv = dn > 0 ? 1.0f / (float)dn : 0.0f;
    ((float2*)x)[(size_t)node * 64 + lane] = make_float2(ax * nv, ay * nv);
}

// ========== MFMA transform: x_norm @ W + bias -> LayerNorm -> ReLU =========
__global__ __launch_bounds__(256) void k_transform_mfma(
    const float* __restrict__ w, const float* __restrict__ bias,
    const float* __restrict__ gamma, const float* __restrict__ beta,
    float* __restrict__ x, int n_nodes) {
    __shared__ short wt[128 * 136];   // wt[col][k], padded stride

    const int tid = threadIdx.x;
    {
        int n = tid & 127;
        for (int k = tid >> 7; k < 128; k += 2)
            wt[n * 136 + k] = f2bf(w[(size_t)k * 128 + n]);
    }
    __syncthreads();

    const int wid = tid >> 6;
    const int l   = tid & 63;
    const int lr  = l & 15;
    const int lk  = l >> 4;

    float bs[8], gm[8], bt[8];
    #pragma unroll
    for (int n = 0; n < 8; ++n) {
        int c = n * 16 + lr;
        bs[n] = bias[c]; gm[n] = gamma[c]; bt[n] = beta[c];
    }

    for (int base = blockIdx.x * 64; base < n_nodes; base += gridDim.x * 64) {
        const int row = base + wid * 16 + lr;
        const bool valid = row < n_nodes;

        short8 af[4];
        #pragma unroll
        for (int kk = 0; kk < 4; ++kk) {
            int k0 = kk * 32 + lk * 8;
            float4 a0{0,0,0,0}, a1{0,0,0,0};
            if (valid) {
                a0 = *(const float4*)(x + (size_t)row * F + k0);
                a1 = *(const float4*)(x + (size_t)row * F + k0 + 4);
            }
            af[kk] = short8{ f2bf(a0.x), f2bf(a0.y), f2bf(a0.z), f2bf(a0.w),
                             f2bf(a1.x), f2bf(a1.y), f2bf(a1.z), f2bf(a1.w) };
        }

        f32x4 acc[8];
        #pragma unroll
        for (int n = 0; n < 8; ++n) acc[n] = f32x4{0, 0, 0, 0};

        #pragma unroll
        for (int kk = 0; kk < 4; ++kk) {
            const int kb = kk * 32 + lk * 8;
            #pragma unroll
            for (int n = 0; n < 8; ++n) {
                short8 bfr = *(const short8*)(&wt[(n * 16 + lr) * 136 + kb]);
                acc[n] = __builtin_amdgcn_mfma_f32_16x16x32_bf16(af[kk], bfr, acc[n], 0, 0, 0);
            }
        }

        float s4[4] = {0,0,0,0}, q4[4] = {0,0,0,0};
        #pragma unroll
        for (int n = 0; n < 8; ++n)
            #pragma unroll
            for (int r = 0; r < 4; ++r) {
                float v = acc[n][r] + bs[n];
                acc[n][r] = v;
                s4[r] += v; q4[r] += v * v;
            }
        #pragma unroll
        for (int m = 1; m < 16; m <<= 1)
            #pragma unroll
            for (int r = 0; r < 4; ++r) {
                s4[r] += __shfl_xor(s4[r], m);
                q4[r] += __shfl_xor(q4[r], m);
            }

        #pragma unroll
        for (int r = 0; r < 4; ++r) {
            float mu   = s4[r] * (1.0f / F);
            float var  = q4[r] * (1.0f / F) - mu * mu;
            float rstd = rsqrtf(var + 1e-5f);
            int rw = base + wid * 16 + lk * 4 + r;
            if (rw < n_nodes) {
                #pragma unroll
                for (int n = 0; n < 8; ++n) {
                    float y = (acc[n][r] - mu) * rstd * gm[n] + bt[n];
                    x[(size_t)rw * F + n * 16 + lr] = fmaxf(y, 0.0f);
                }
            }
        }
    }
}

extern "C" void kernel_launch(void* const* d_in, const int* in_sizes, int n_in,
                              void* d_out, int out_size, void* d_ws, size_t ws_size,
                              hipStream_t stream) {
    const float* h      = (const float*)d_in[0];
    const float* weight = (const float*)d_in[1];
    const float* bias   = (const float*)d_in[2];
    const float* gamma  = (const float*)d_in[3];
    const float* beta   = (const float*)d_in[4];
    const int*   src    = (const int*)d_in[5];
    const int*   dst    = (const int*)d_in[6];

    const int n_nodes = in_sizes[0] / F;
    const int n_edges = in_sizes[5];

    float* x = (float*)d_out;   // N x 128: x_norm after gather, output after transform

    // bucket shift: bucket = dst >> bshift; need nb <= MAXNB and bshift <= 6
    int bshift = 5;
    while (bshift <= 6 && ((n_nodes + (1 << bshift) - 1) >> bshift) > MAXNB) ++bshift;
    const int nb = (n_nodes + (1 << bshift) - 1) >> bshift;
    const bool shift_ok = (((n_nodes + (1 << bshift) - 1) >> bshift) <= MAXNB) &&
                          (n_nodes <= (1 << 26));

    // workspace (ints): deg[N] | offs[N] | esrc[E] | hb[N*64 u32] |
    //   new path tail:  bsum[512] | mat[nb*NBLK] | binned[E u32]
    //   fallback tail:  bsum[512] | cursor[N]
    int* deg    = (int*)d_ws;
    int* offs   = deg + n_nodes;
    int* esrc   = offs + n_nodes;
    unsigned* hb = (unsigned*)(esrc + n_edges);
    int* bsum   = (int*)(hb + (size_t)n_nodes * 64);
    int* mat    = bsum + 512;
    unsigned* binned = (unsigned*)(mat + (size_t)nb * NBLK);
    int* cursor = mat;   // fallback reuses mat slot

    size_t need_common = ((size_t)2 * n_nodes + (size_t)n_edges + 512) * sizeof(int)
                       + (size_t)n_nodes * 64 * sizeof(unsigned);
    size_t need_new  = need_common + ((size_t)nb * NBLK + (size_t)n_edges) * sizeof(int);
    size_t need_fall = need_common + (size_t)n_nodes * sizeof(int);
    bool use_new = shift_ok && ws_size >= need_new;

    // bf16 h copy
    {
        int total8 = n_nodes * F / 8;
        k_h2b<<<(total8 + 255) / 256, 256, 0, stream>>>(h, hb, total8);
    }

    if (use_new) {
        const int epb = (n_edges + NBLK - 1) / NBLK;
        const int len = nb * NBLK;
        const int nscan = (len + SCANB - 1) / SCANB;   // <= 512 by construction
        k_part_hist<<<NBLK, 256, 0, stream>>>(dst, mat, n_edges, nb, bshift, epb);
        k_scan_a<<<nscan, SCANB, 0, stream>>>(mat, mat, bsum, len);
        k_scan_b<<<1, 512, 0, stream>>>(bsum, nscan);
        k_scan_c<<<nscan, SCANB, 0, stream>>>(mat, bsum, len);
        k_part_scatter<<<NBLK, 256, 0, stream>>>(src, dst, mat, binned,
                                                 n_edges, nb, bshift, epb);
        k_bin_to_csr<<<nb, 256, 0, stream>>>(binned, mat, deg, offs, esrc,
                                             n_edges, n_nodes, nb, bshift);
    } else if (ws_size >= need_fall) {
        const int nscan = (n_nodes + SCANB - 1) / SCANB;
        hipMemsetAsync(deg, 0, (size_t)n_nodes * sizeof(int), stream);
        hipMemsetAsync(cursor, 0, (size_t)n_nodes * sizeof(int), stream);
        k_hist<<<(n_edges + 255) / 256, 256, 0, stream>>>(dst, deg, n_edges);
        k_scan_a<<<nscan, SCANB, 0, stream>>>(deg, offs, bsum, n_nodes);
        k_scan_b<<<1, 512, 0, stream>>>(bsum, nscan);
        k_scan_c<<<nscan, SCANB, 0, stream>>>(offs, bsum, n_nodes);
        k_scatter_idx<<<(n_edges + 255) / 256, 256, 0, stream>>>(
            src, dst, offs, cursor, esrc, n_edges);
    }

    int gblocks = (int)(((size_t)n_nodes * 64 + 255) / 256);
    k_gather_bf16<<<gblocks, 256, 0, stream>>>(hb, esrc, offs, deg, x, n_nodes);

    int tblocks = (n_nodes + 63) / 64;
    k_transform_mfma<<<tblocks, 256, 0, stream>>>(weight, bias, gamma, beta, x, n_nodes);
}